// Round 1
// baseline (308.385 us; speedup 1.0000x reference)
//
#include <hip/hip_runtime.h>

#define N_NODES 100000
#define DEG 16

typedef __attribute__((ext_vector_type(8))) short short8;   // 8 bf16 in 4 VGPRs
typedef __attribute__((ext_vector_type(4))) float f32x4;

__device__ inline unsigned short f2bf(float f) {
    union { float f; unsigned u; } v; v.f = f;
    unsigned u = v.u;
    u += 0x7FFFu + ((u >> 16) & 1u);    // round-to-nearest-even
    return (unsigned short)(u >> 16);
}

// Y[M,64] = X[M,K] @ W[K,64], bf16 MFMA with fp32 accumulate.
// One wave computes a 16-row x 64-col tile (4 accumulators of 16x16).
// W is staged into LDS in B-fragment order so each lane's 8 bf16 B values
// are one contiguous ds_read_b128.
template<int K>
__global__ __launch_bounds__(256) void gemm_n64(const float* __restrict__ X,
                                                const float* __restrict__ W,
                                                float* __restrict__ Y, int M)
{
    __shared__ unsigned short wfrag[K * 64];
    const int tid = threadIdx.x;

    // Stage W -> LDS, pre-swizzled into fragment order:
    // idx = ((kb*4 + ct)*64 + lane)*8 + j  holds  W[kb*32 + (lane>>4)*8 + j][ct*16 + (lane&15)]
    for (int idx = tid; idx < K * 64; idx += 256) {
        int j    = idx & 7;
        int lane = (idx >> 3) & 63;
        int ct   = (idx >> 9) & 3;
        int kb   = idx >> 11;
        int k    = kb * 32 + ((lane >> 4) << 3) + j;
        int col  = ct * 16 + (lane & 15);
        wfrag[idx] = f2bf(W[k * 64 + col]);
    }
    __syncthreads();

    const int lane = tid & 63;
    const int wid  = tid >> 6;
    const int q    = lane >> 4;      // quad 0..3
    const int l16  = lane & 15;
    const int numTiles = M >> 4;     // M = 100000 -> 6250 exact
    const int stride = gridDim.x * 4;

    for (int t = blockIdx.x * 4 + wid; t < numTiles; t += stride) {
        const int rowbase = t << 4;
        const float* xp = X + (size_t)(rowbase + l16) * K + q * 8;
        f32x4 acc0 = {0.f,0.f,0.f,0.f};
        f32x4 acc1 = {0.f,0.f,0.f,0.f};
        f32x4 acc2 = {0.f,0.f,0.f,0.f};
        f32x4 acc3 = {0.f,0.f,0.f,0.f};

        #pragma unroll
        for (int kb = 0; kb < K / 32; ++kb) {
            // A fragment: X[rowbase+l16][kb*32 + q*8 + 0..7], fp32 -> bf16
            float4 a0 = *(const float4*)(xp + kb * 32);
            float4 a1 = *(const float4*)(xp + kb * 32 + 4);
            short8 af;
            af[0] = (short)f2bf(a0.x); af[1] = (short)f2bf(a0.y);
            af[2] = (short)f2bf(a0.z); af[3] = (short)f2bf(a0.w);
            af[4] = (short)f2bf(a1.x); af[5] = (short)f2bf(a1.y);
            af[6] = (short)f2bf(a1.z); af[7] = (short)f2bf(a1.w);

            const short8* wp = (const short8*)&wfrag[(size_t)(kb * 4) * 64 * 8 + (size_t)lane * 8];
            // ct blocks are 64 short8's apart
            acc0 = __builtin_amdgcn_mfma_f32_16x16x32_bf16(af, wp[0 * 64], acc0, 0, 0, 0);
            acc1 = __builtin_amdgcn_mfma_f32_16x16x32_bf16(af, wp[1 * 64], acc1, 0, 0, 0);
            acc2 = __builtin_amdgcn_mfma_f32_16x16x32_bf16(af, wp[2 * 64], acc2, 0, 0, 0);
            acc3 = __builtin_amdgcn_mfma_f32_16x16x32_bf16(af, wp[3 * 64], acc3, 0, 0, 0);
        }

        // D layout: lane holds D[q*4 + r][ct*16 + l16]
        float* yp = Y + (size_t)rowbase * 64;
        #pragma unroll
        for (int r = 0; r < 4; ++r) {
            int rr = (q * 4 + r) * 64 + l16;
            yp[rr + 0 * 16] = acc0[r];
            yp[rr + 1 * 16] = acc1[r];
            yp[rr + 2 * 16] = acc2[r];
            yp[rr + 3 * 16] = acc3[r];
        }
    }
}

// out[row][:] = (relu?) sum_{e in row} vals[e] * B[colind[e]][:]
// One wave handles 4 rows: quad q -> row, 16 lanes x float4 -> 64 cols.
template<bool RELU>
__global__ __launch_bounds__(256) void spmm16(const int* __restrict__ colind,
                                              const float* __restrict__ vals,
                                              const float* __restrict__ B,
                                              float* __restrict__ Yout)
{
    const int tid  = threadIdx.x;
    const int lane = tid & 63;
    const int wid  = tid >> 6;
    const int q    = lane >> 4;
    const int c4   = (lane & 15) << 2;     // float col base
    const int row  = (blockIdx.x * 4 + wid) * 4 + q;   // grid sized exactly

    const int*   ci = colind + (size_t)row * DEG;
    const float* vv = vals   + (size_t)row * DEG;

    float ax = 0.f, ay = 0.f, az = 0.f, aw = 0.f;
    #pragma unroll
    for (int e = 0; e < DEG; ++e) {
        int   c = ci[e];
        float v = vv[e];
        float4 b = *(const float4*)(B + (size_t)c * 64 + c4);
        ax += v * b.x; ay += v * b.y; az += v * b.z; aw += v * b.w;
    }
    if (RELU) {
        ax = fmaxf(ax, 0.f); ay = fmaxf(ay, 0.f);
        az = fmaxf(az, 0.f); aw = fmaxf(aw, 0.f);
    }
    float4 o; o.x = ax; o.y = ay; o.z = az; o.w = aw;
    *(float4*)(Yout + (size_t)row * 64 + c4) = o;
}

extern "C" void kernel_launch(void* const* d_in, const int* in_sizes, int n_in,
                              void* d_out, int out_size, void* d_ws, size_t ws_size,
                              hipStream_t stream) {
    const float* X      = (const float*)d_in[0];   // [N,256]
    const float* W1     = (const float*)d_in[1];   // [256,64]
    const float* W2     = (const float*)d_in[2];   // [64,64]
    const float* vals   = (const float*)d_in[3];   // [NNZ]
    // d_in[4] = rowptr (fixed degree 16, unused)
    const int*   colind = (const int*)d_in[5];     // [NNZ]
    float*       out    = (float*)d_out;           // [N,64]

    float* h  = (float*)d_ws;                      // [N,64] 25.6 MB
    float* h2 = h + (size_t)N_NODES * 64;          // [N,64] 25.6 MB
    float* o1 = h;                                 // reuse h (dead after spmm1)

    // h = X @ W1   (bf16 MFMA, HBM-bound on X read)
    hipLaunchKernelGGL((gemm_n64<256>), dim3(1024), dim3(256), 0, stream, X, W1, h, N_NODES);
    // h2 = relu(A @ h)
    hipLaunchKernelGGL((spmm16<true>), dim3(6250), dim3(256), 0, stream, colind, vals, h, h2);
    // o1 = h2 @ W2
    hipLaunchKernelGGL((gemm_n64<64>), dim3(1024), dim3(256), 0, stream, h2, W2, o1, N_NODES);
    // out = A @ o1
    hipLaunchKernelGGL((spmm16<false>), dim3(6250), dim3(256), 0, stream, colind, vals, o1, out);
}

// Round 2
// 267.394 us; speedup vs baseline: 1.1533x; 1.1533x over previous
//
#include <hip/hip_runtime.h>

#define N_NODES 100000
#define DEG 16

typedef __attribute__((ext_vector_type(8))) short short8;   // 8 bf16 in 4 VGPRs
typedef __attribute__((ext_vector_type(4))) float f32x4;

__device__ inline unsigned short f2bf(float f) {
    union { float f; unsigned u; } v; v.f = f;
    unsigned u = v.u;
    u += 0x7FFFu + ((u >> 16) & 1u);    // RNE
    return (unsigned short)(u >> 16);
}
__device__ inline float bflo(unsigned u) {   // low bf16 of packed pair -> f32
    union { unsigned u; float f; } v; v.u = u << 16; return v.f;
}
__device__ inline float bfhi(unsigned u) {   // high bf16 of packed pair -> f32
    union { unsigned u; float f; } v; v.u = u & 0xFFFF0000u; return v.f;
}

// ---------------------------------------------------------------------------
// GEMM1: Y[M,64](bf16) = X[M,256](fp32) @ W[256,64](fp32), bf16 MFMA fp32 acc.
// Block = 4 waves, 64 rows/block (16 rows/wave). Coalesced staging via LDS.
// ---------------------------------------------------------------------------
__global__ __launch_bounds__(256) void gemm1_k256(const float* __restrict__ X,
                                                  const float* __restrict__ W,
                                                  unsigned short* __restrict__ Y,
                                                  int M)
{
    constexpr int K = 256;
    constexpr int KPAD = K + 8;                    // ushort stride (528 B, 16B-aligned)
    __shared__ unsigned short wfrag[K * 64];       // 32 KB, B-fragment order
    __shared__ unsigned short stage[4][16 * KPAD]; // 33 KB, per-wave A tiles

    const int tid = threadIdx.x;
    // Stage W in B-fragment order: wfrag[((kb*4+ct)*64+lane)*8+j] =
    //   W[kb*32 + (lane>>4)*8 + j][ct*16 + (lane&15)]
    for (int idx = tid; idx < K * 64; idx += 256) {
        int j    = idx & 7;
        int lane = (idx >> 3) & 63;
        int ct   = (idx >> 9) & 3;
        int kb   = idx >> 11;
        int k    = kb * 32 + ((lane >> 4) << 3) + j;
        int col  = ct * 16 + (lane & 15);
        wfrag[idx] = f2bf(W[k * 64 + col]);
    }
    __syncthreads();

    const int lane = tid & 63;
    const int wid  = tid >> 6;
    const int q    = lane >> 4;
    const int l16  = lane & 15;
    const int rowbase = blockIdx.x * 64 + wid * 16;
    unsigned short* st = stage[wid];

    // Coalesced stage: iteration r loads one full row (64 lanes x float4 = 1 KB)
    #pragma unroll
    for (int r = 0; r < 16; ++r) {
        int rg = rowbase + r; if (rg > M - 1) rg = M - 1;
        float4 x4 = *(const float4*)(X + (size_t)rg * K + lane * 4);
        ushort4 s;
        s.x = f2bf(x4.x); s.y = f2bf(x4.y); s.z = f2bf(x4.z); s.w = f2bf(x4.w);
        *(ushort4*)&st[r * KPAD + lane * 4] = s;
    }
    // per-wave private LDS slice: no __syncthreads needed, lgkmcnt orders it

    f32x4 acc0 = {0,0,0,0}, acc1 = {0,0,0,0}, acc2 = {0,0,0,0}, acc3 = {0,0,0,0};
    #pragma unroll
    for (int kb = 0; kb < K / 32; ++kb) {
        short8 af = *(const short8*)&st[l16 * KPAD + kb * 32 + q * 8];
        const short8* wp = (const short8*)&wfrag[((kb * 4) * 64 + lane) * 8];
        acc0 = __builtin_amdgcn_mfma_f32_16x16x32_bf16(af, wp[0 * 64], acc0, 0, 0, 0);
        acc1 = __builtin_amdgcn_mfma_f32_16x16x32_bf16(af, wp[1 * 64], acc1, 0, 0, 0);
        acc2 = __builtin_amdgcn_mfma_f32_16x16x32_bf16(af, wp[2 * 64], acc2, 0, 0, 0);
        acc3 = __builtin_amdgcn_mfma_f32_16x16x32_bf16(af, wp[3 * 64], acc3, 0, 0, 0);
    }

    // Epilogue: repack D (row=q*4+r, col=ct*16+l16) -> bf16 via LDS, then
    // coalesced uint2 global stores. Reuse stage slice (frag reads are done).
    unsigned short* ob = st;   // use [16][72] region
    #pragma unroll
    for (int r = 0; r < 4; ++r) {
        int rr = (q * 4 + r) * 72 + l16;
        ob[rr + 0 * 16] = f2bf(acc0[r]);
        ob[rr + 1 * 16] = f2bf(acc1[r]);
        ob[rr + 2 * 16] = f2bf(acc2[r]);
        ob[rr + 3 * 16] = f2bf(acc3[r]);
    }
    #pragma unroll
    for (int i = 0; i < 4; ++i) {
        int row = i * 4 + q;
        int rg  = rowbase + row;
        if (rg < M) {
            uint2 v = *(const uint2*)&ob[row * 72 + l16 * 4];
            *(uint2*)(Y + (size_t)rg * 64 + l16 * 4) = v;
        }
    }
}

// ---------------------------------------------------------------------------
// GEMM2: Y[M,64](bf16) = Xb[M,64](bf16) @ W[64,64](fp32). Same structure, K=64.
// ---------------------------------------------------------------------------
__global__ __launch_bounds__(256) void gemm2_k64(const unsigned short* __restrict__ Xb,
                                                 const float* __restrict__ W,
                                                 unsigned short* __restrict__ Y,
                                                 int M)
{
    constexpr int K = 64;
    constexpr int KPAD = K + 8;                    // 72 ushorts = 144 B
    __shared__ unsigned short wfrag[K * 64];       // 8 KB
    __shared__ unsigned short stage[4][16 * KPAD]; // 9 KB

    const int tid = threadIdx.x;
    for (int idx = tid; idx < K * 64; idx += 256) {
        int j    = idx & 7;
        int lane = (idx >> 3) & 63;
        int ct   = (idx >> 9) & 3;
        int kb   = idx >> 11;
        int k    = kb * 32 + ((lane >> 4) << 3) + j;
        int col  = ct * 16 + (lane & 15);
        wfrag[idx] = f2bf(W[k * 64 + col]);
    }
    __syncthreads();

    const int lane = tid & 63;
    const int wid  = tid >> 6;
    const int q    = lane >> 4;
    const int l16  = lane & 15;
    const int rowbase = blockIdx.x * 64 + wid * 16;
    unsigned short* st = stage[wid];

    // Coalesced stage: 4 iterations, each covers 4 rows (64 lanes x uint2 = 512 B)
    #pragma unroll
    for (int i = 0; i < 4; ++i) {
        int row = i * 4 + q;
        int rg  = rowbase + row; if (rg > M - 1) rg = M - 1;
        uint2 v = *(const uint2*)(Xb + (size_t)rg * 64 + l16 * 4);
        *(uint2*)&st[row * KPAD + l16 * 4] = v;
    }

    f32x4 acc0 = {0,0,0,0}, acc1 = {0,0,0,0}, acc2 = {0,0,0,0}, acc3 = {0,0,0,0};
    #pragma unroll
    for (int kb = 0; kb < K / 32; ++kb) {
        short8 af = *(const short8*)&st[l16 * KPAD + kb * 32 + q * 8];
        const short8* wp = (const short8*)&wfrag[((kb * 4) * 64 + lane) * 8];
        acc0 = __builtin_amdgcn_mfma_f32_16x16x32_bf16(af, wp[0 * 64], acc0, 0, 0, 0);
        acc1 = __builtin_amdgcn_mfma_f32_16x16x32_bf16(af, wp[1 * 64], acc1, 0, 0, 0);
        acc2 = __builtin_amdgcn_mfma_f32_16x16x32_bf16(af, wp[2 * 64], acc2, 0, 0, 0);
        acc3 = __builtin_amdgcn_mfma_f32_16x16x32_bf16(af, wp[3 * 64], acc3, 0, 0, 0);
    }

    unsigned short* ob = st;
    #pragma unroll
    for (int r = 0; r < 4; ++r) {
        int rr = (q * 4 + r) * 72 + l16;
        ob[rr + 0 * 16] = f2bf(acc0[r]);
        ob[rr + 1 * 16] = f2bf(acc1[r]);
        ob[rr + 2 * 16] = f2bf(acc2[r]);
        ob[rr + 3 * 16] = f2bf(acc3[r]);
    }
    #pragma unroll
    for (int i = 0; i < 4; ++i) {
        int row = i * 4 + q;
        int rg  = rowbase + row;
        if (rg < M) {
            uint2 v = *(const uint2*)&ob[row * 72 + l16 * 4];
            *(uint2*)(Y + (size_t)rg * 64 + l16 * 4) = v;
        }
    }
}

// ---------------------------------------------------------------------------
// SpMM: out[row][:] = (relu?) sum_e vals[e] * B[colind[e]][:], B is bf16 [N][64].
// Wave = 4 rows (quad q -> row); lane l16 -> 4 cols via one uint2 (8 B) gather,
// so each quad's gather is one contiguous 128 B row (2 cache lines).
// ---------------------------------------------------------------------------
template<bool RELU, bool OUT_BF16>
__global__ __launch_bounds__(256) void spmm16_bf16(const int* __restrict__ colind,
                                                   const float* __restrict__ vals,
                                                   const unsigned short* __restrict__ B,
                                                   void* __restrict__ outp)
{
    const int tid  = threadIdx.x;
    const int lane = tid & 63;
    const int wid  = tid >> 6;
    const int q    = lane >> 4;
    const int l16  = lane & 15;
    const int row  = (blockIdx.x * 4 + wid) * 4 + q;   // grid covers N exactly

    const int*   ci = colind + (size_t)row * DEG;
    const float* vv = vals   + (size_t)row * DEG;

    float a0 = 0.f, a1 = 0.f, a2 = 0.f, a3 = 0.f;
    #pragma unroll
    for (int e = 0; e < DEG; ++e) {
        int   c = ci[e];
        float v = vv[e];
        uint2 b = *(const uint2*)(B + (size_t)c * 64 + l16 * 4);
        a0 += v * bflo(b.x); a1 += v * bfhi(b.x);
        a2 += v * bflo(b.y); a3 += v * bfhi(b.y);
    }
    if (RELU) {
        a0 = fmaxf(a0, 0.f); a1 = fmaxf(a1, 0.f);
        a2 = fmaxf(a2, 0.f); a3 = fmaxf(a3, 0.f);
    }
    if (OUT_BF16) {
        ushort4 o; o.x = f2bf(a0); o.y = f2bf(a1); o.z = f2bf(a2); o.w = f2bf(a3);
        *(ushort4*)((unsigned short*)outp + (size_t)row * 64 + l16 * 4) = o;
    } else {
        float4 o; o.x = a0; o.y = a1; o.z = a2; o.w = a3;
        *(float4*)((float*)outp + (size_t)row * 64 + l16 * 4) = o;
    }
}

extern "C" void kernel_launch(void* const* d_in, const int* in_sizes, int n_in,
                              void* d_out, int out_size, void* d_ws, size_t ws_size,
                              hipStream_t stream) {
    const float* X      = (const float*)d_in[0];   // [N,256]
    const float* W1     = (const float*)d_in[1];   // [256,64]
    const float* W2     = (const float*)d_in[2];   // [64,64]
    const float* vals   = (const float*)d_in[3];   // [NNZ]
    // d_in[4] = rowptr (fixed degree, unused)
    const int*   colind = (const int*)d_in[5];     // [NNZ]
    float*       out    = (float*)d_out;           // [N,64] fp32

    unsigned short* h  = (unsigned short*)d_ws;            // [N,64] bf16, 12.8 MB
    unsigned short* h2 = h + (size_t)N_NODES * 64;         // [N,64] bf16
    unsigned short* o1 = h;                                // reuse (h dead after spmm1)

    const int gemm_grid = (N_NODES + 63) / 64;   // 1563

    // h = bf16(X @ W1)
    hipLaunchKernelGGL(gemm1_k256, dim3(gemm_grid), dim3(256), 0, stream, X, W1, h, N_NODES);
    // h2 = bf16(relu(A @ h))
    hipLaunchKernelGGL((spmm16_bf16<true, true>), dim3(6250), dim3(256), 0, stream,
                       colind, vals, h, (void*)h2);
    // o1 = bf16(h2 @ W2)
    hipLaunchKernelGGL(gemm2_k64, dim3(gemm_grid), dim3(256), 0, stream, h2, W2, o1, N_NODES);
    // out = A @ o1  (fp32 out)
    hipLaunchKernelGGL((spmm16_bf16<false, false>), dim3(6250), dim3(256), 0, stream,
                       colind, vals, o1, (void*)out);
}

// Round 3
// 251.008 us; speedup vs baseline: 1.2286x; 1.0653x over previous
//
#include <hip/hip_runtime.h>

#define N_NODES 100000
#define DEG 16
#define NT1 6250              // 16-row tiles in gemm1 (100000/16 exact)
#define G1_BLOCKS 512         // 2 blocks/CU, all resident
#define G1_WSTRIDE (G1_BLOCKS * 4)

typedef __attribute__((ext_vector_type(8))) short short8;   // 8 bf16
typedef __attribute__((ext_vector_type(4))) float f32x4;

__device__ inline unsigned short f2bf(float f) {
    union { float f; unsigned u; } v; v.f = f;
    unsigned u = v.u;
    u += 0x7FFFu + ((u >> 16) & 1u);    // RNE
    return (unsigned short)(u >> 16);
}
__device__ inline float bflo(unsigned u) {
    union { unsigned u; float f; } v; v.u = u << 16; return v.f;
}
__device__ inline float bfhi(unsigned u) {
    union { unsigned u; float f; } v; v.u = u & 0xFFFF0000u; return v.f;
}

// ---------------------------------------------------------------------------
// GEMM1: Y[M,64](bf16) = X[M,256](fp32) @ W[256,64](fp32).
// Persistent: 512 blocks (2/CU), each wave ~3 tiles of 16 rows.
// Register-level prefetch: next tile's 16x float4 loads in flight during
// current tile's convert/LDS/MFMA/store.
// ---------------------------------------------------------------------------
__global__ __launch_bounds__(256, 2) void gemm1_k256(const float* __restrict__ X,
                                                     const float* __restrict__ W,
                                                     unsigned short* __restrict__ Y)
{
    constexpr int K = 256;
    constexpr int KPAD = 264;
    __shared__ unsigned short wfrag[K * 64];       // 32 KB, B-fragment order
    __shared__ unsigned short stage[4][16 * KPAD]; // 33 KB

    const int tid = threadIdx.x;
    // wfrag[((kb*4+ct)*64+lane)*8+j] = W[kb*32+(lane>>4)*8+j][ct*16+(lane&15)]
    for (int idx = tid; idx < K * 64; idx += 256) {
        int j    = idx & 7;
        int ln   = (idx >> 3) & 63;
        int ct   = (idx >> 9) & 3;
        int kb   = idx >> 11;
        int k    = kb * 32 + ((ln >> 4) << 3) + j;
        int col  = ct * 16 + (ln & 15);
        wfrag[idx] = f2bf(W[k * 64 + col]);
    }
    __syncthreads();

    const int lane = tid & 63;
    const int wid  = tid >> 6;
    const int q    = lane >> 4;
    const int l16  = lane & 15;
    unsigned short* st = stage[wid];

    int t = blockIdx.x * 4 + wid;          // 0..2047 < NT1, prologue always valid
    float4 pf[16];
    {
        const float* xb = X + (size_t)t * 16 * K + lane * 4;
        #pragma unroll
        for (int r = 0; r < 16; ++r) pf[r] = *(const float4*)(xb + (size_t)r * K);
    }

    while (t < NT1) {
        // convert current tile (waits vmcnt for pf)
        ushort4 cv[16];
        #pragma unroll
        for (int r = 0; r < 16; ++r) {
            cv[r].x = f2bf(pf[r].x); cv[r].y = f2bf(pf[r].y);
            cv[r].z = f2bf(pf[r].z); cv[r].w = f2bf(pf[r].w);
        }
        // issue next tile's loads (in flight during the rest of this iter)
        int tn = t + G1_WSTRIDE;
        if (tn < NT1) {
            const float* xb = X + (size_t)tn * 16 * K + lane * 4;
            #pragma unroll
            for (int r = 0; r < 16; ++r) pf[r] = *(const float4*)(xb + (size_t)r * K);
        }
        // stage current tile to LDS
        #pragma unroll
        for (int r = 0; r < 16; ++r)
            *(ushort4*)&st[r * KPAD + lane * 4] = cv[r];

        f32x4 acc0 = {0,0,0,0}, acc1 = {0,0,0,0}, acc2 = {0,0,0,0}, acc3 = {0,0,0,0};
        #pragma unroll
        for (int kb = 0; kb < K / 32; ++kb) {
            short8 af = *(const short8*)&st[l16 * KPAD + kb * 32 + q * 8];
            const short8* wp = (const short8*)&wfrag[(size_t)((kb * 4) * 64 + lane) * 8];
            acc0 = __builtin_amdgcn_mfma_f32_16x16x32_bf16(af, wp[0 * 64], acc0, 0, 0, 0);
            acc1 = __builtin_amdgcn_mfma_f32_16x16x32_bf16(af, wp[1 * 64], acc1, 0, 0, 0);
            acc2 = __builtin_amdgcn_mfma_f32_16x16x32_bf16(af, wp[2 * 64], acc2, 0, 0, 0);
            acc3 = __builtin_amdgcn_mfma_f32_16x16x32_bf16(af, wp[3 * 64], acc3, 0, 0, 0);
        }

        // epilogue: repack D -> bf16 rows via LDS (stride 72), coalesced stores
        #pragma unroll
        for (int r = 0; r < 4; ++r) {
            int rr = (q * 4 + r) * 72 + l16;
            st[rr + 0 * 16] = f2bf(acc0[r]);
            st[rr + 1 * 16] = f2bf(acc1[r]);
            st[rr + 2 * 16] = f2bf(acc2[r]);
            st[rr + 3 * 16] = f2bf(acc3[r]);
        }
        const int rowbase = t * 16;
        #pragma unroll
        for (int i = 0; i < 4; ++i) {
            int row = i * 4 + q;
            uint2 v = *(const uint2*)&st[row * 72 + l16 * 4];
            *(uint2*)(Y + (size_t)(rowbase + row) * 64 + l16 * 4) = v;
        }
        t = tn;
    }
}

// ---------------------------------------------------------------------------
// Fused SpMM1 + ReLU + GEMM2:
//   h2_rows = relu(A @ h) computed per 16-row wave-tile (registers -> LDS),
//   then o1 = h2_rows @ W2 via MFMA (K=64), stored bf16.
// ---------------------------------------------------------------------------
__global__ __launch_bounds__(256) void spmm_gemm2(const int* __restrict__ colind,
                                                  const float* __restrict__ vals,
                                                  const unsigned short* __restrict__ Bh,
                                                  const float* __restrict__ W2,
                                                  unsigned short* __restrict__ Y)
{
    constexpr int K = 64;
    constexpr int KPAD = 72;
    __shared__ unsigned short wfrag[K * 64];       // 8 KB
    __shared__ unsigned short stage[4][16 * KPAD]; // 9 KB

    const int tid = threadIdx.x;
    for (int idx = tid; idx < K * 64; idx += 256) {
        int j    = idx & 7;
        int ln   = (idx >> 3) & 63;
        int ct   = (idx >> 9) & 3;
        int kb   = idx >> 11;
        int k    = kb * 32 + ((ln >> 4) << 3) + j;
        int col  = ct * 16 + (ln & 15);
        wfrag[idx] = f2bf(W2[k * 64 + col]);
    }
    __syncthreads();

    const int lane = tid & 63;
    const int wid  = tid >> 6;
    const int q    = lane >> 4;
    const int l16  = lane & 15;
    unsigned short* st = stage[wid];
    const int base = blockIdx.x * 64 + wid * 16;   // grid = 1563 -> covers 100032

    // SpMM + ReLU: 16 rows per wave, 4 rows per pass (quad q -> row)
    for (int i = 0; i < 4; ++i) {
        int row = base + i * 4 + q;
        int rc  = row < N_NODES ? row : N_NODES - 1;
        const int*   ci = colind + (size_t)rc * DEG;
        const float* vv = vals   + (size_t)rc * DEG;
        float a0 = 0.f, a1 = 0.f, a2 = 0.f, a3 = 0.f;
        #pragma unroll
        for (int e = 0; e < DEG; ++e) {
            int   c = ci[e];
            float v = vv[e];
            uint2 b = *(const uint2*)(Bh + (size_t)c * 64 + l16 * 4);
            a0 += v * bflo(b.x); a1 += v * bfhi(b.x);
            a2 += v * bflo(b.y); a3 += v * bfhi(b.y);
        }
        a0 = fmaxf(a0, 0.f); a1 = fmaxf(a1, 0.f);
        a2 = fmaxf(a2, 0.f); a3 = fmaxf(a3, 0.f);
        ushort4 s;
        s.x = f2bf(a0); s.y = f2bf(a1); s.z = f2bf(a2); s.w = f2bf(a3);
        *(ushort4*)&st[(i * 4 + q) * KPAD + l16 * 4] = s;
    }
    // wave-private LDS slice: DS ops are in-order per wave, no barrier needed

    f32x4 acc0 = {0,0,0,0}, acc1 = {0,0,0,0}, acc2 = {0,0,0,0}, acc3 = {0,0,0,0};
    #pragma unroll
    for (int kb = 0; kb < K / 32; ++kb) {
        short8 af = *(const short8*)&st[l16 * KPAD + kb * 32 + q * 8];
        const short8* wp = (const short8*)&wfrag[(size_t)((kb * 4) * 64 + lane) * 8];
        acc0 = __builtin_amdgcn_mfma_f32_16x16x32_bf16(af, wp[0 * 64], acc0, 0, 0, 0);
        acc1 = __builtin_amdgcn_mfma_f32_16x16x32_bf16(af, wp[1 * 64], acc1, 0, 0, 0);
        acc2 = __builtin_amdgcn_mfma_f32_16x16x32_bf16(af, wp[2 * 64], acc2, 0, 0, 0);
        acc3 = __builtin_amdgcn_mfma_f32_16x16x32_bf16(af, wp[3 * 64], acc3, 0, 0, 0);
    }

    #pragma unroll
    for (int r = 0; r < 4; ++r) {
        int rr = (q * 4 + r) * KPAD + l16;
        st[rr + 0 * 16] = f2bf(acc0[r]);
        st[rr + 1 * 16] = f2bf(acc1[r]);
        st[rr + 2 * 16] = f2bf(acc2[r]);
        st[rr + 3 * 16] = f2bf(acc3[r]);
    }
    #pragma unroll
    for (int i = 0; i < 4; ++i) {
        int row = base + i * 4 + q;
        if (row < N_NODES) {
            uint2 v = *(const uint2*)&st[(i * 4 + q) * KPAD + l16 * 4];
            *(uint2*)(Y + (size_t)row * 64 + l16 * 4) = v;
        }
    }
}

// ---------------------------------------------------------------------------
// SpMM2: out(fp32) = A @ o1(bf16). Wave = 4 rows, quad gather = one 128 B line.
// ---------------------------------------------------------------------------
__global__ __launch_bounds__(256) void spmm_out(const int* __restrict__ colind,
                                                const float* __restrict__ vals,
                                                const unsigned short* __restrict__ B,
                                                float* __restrict__ out)
{
    const int tid  = threadIdx.x;
    const int lane = tid & 63;
    const int wid  = tid >> 6;
    const int q    = lane >> 4;
    const int l16  = lane & 15;
    const int row  = (blockIdx.x * 4 + wid) * 4 + q;   // grid covers N exactly

    const int*   ci = colind + (size_t)row * DEG;
    const float* vv = vals   + (size_t)row * DEG;

    float a0 = 0.f, a1 = 0.f, a2 = 0.f, a3 = 0.f;
    #pragma unroll
    for (int e = 0; e < DEG; ++e) {
        int   c = ci[e];
        float v = vv[e];
        uint2 b = *(const uint2*)(B + (size_t)c * 64 + l16 * 4);
        a0 += v * bflo(b.x); a1 += v * bfhi(b.x);
        a2 += v * bflo(b.y); a3 += v * bfhi(b.y);
    }
    float4 o; o.x = a0; o.y = a1; o.z = a2; o.w = a3;
    *(float4*)(out + (size_t)row * 64 + l16 * 4) = o;
}

extern "C" void kernel_launch(void* const* d_in, const int* in_sizes, int n_in,
                              void* d_out, int out_size, void* d_ws, size_t ws_size,
                              hipStream_t stream) {
    const float* X      = (const float*)d_in[0];   // [N,256]
    const float* W1     = (const float*)d_in[1];   // [256,64]
    const float* W2     = (const float*)d_in[2];   // [64,64]
    const float* vals   = (const float*)d_in[3];   // [NNZ]
    // d_in[4] = rowptr (fixed degree, unused)
    const int*   colind = (const int*)d_in[5];     // [NNZ]
    float*       out    = (float*)d_out;           // [N,64] fp32

    unsigned short* h  = (unsigned short*)d_ws;        // [N,64] bf16
    unsigned short* o1 = h + (size_t)N_NODES * 64;     // [N,64] bf16 (MUST not alias h)

    // h = bf16(X @ W1)  — persistent, pipelined
    hipLaunchKernelGGL(gemm1_k256, dim3(G1_BLOCKS), dim3(256), 0, stream, X, W1, h);
    // o1 = bf16( relu(A @ h) @ W2 )  — fused
    hipLaunchKernelGGL(spmm_gemm2, dim3((N_NODES + 63) / 64), dim3(256), 0, stream,
                       colind, vals, h, W2, o1);
    // out = A @ o1  (fp32)
    hipLaunchKernelGGL(spmm_out, dim3(N_NODES / 16), dim3(256), 0, stream,
                       colind, vals, o1, out);
}